// Round 1
// baseline (1961.692 us; speedup 1.0000x reference)
//
#include <hip/hip_runtime.h>

constexpr int N_NODES = 50000;
constexpr int N_EDGES = 800000;
constexpr int HIDDEN  = 128;
constexpr float RSQRT_D = 0.17677669529663687f;  // 1/sqrt(32)
constexpr int Y_SIZE = N_NODES * HIDDEN;         // 6,400,000

// ---- ws layout (float offsets). Aliasing: out<->q (q dead after k_alpha),
// agg<->k (k dead after k_alpha; agg zeroed by a memset between them). ----
constexpr size_t OFF_Q     = 0;
constexpr size_t OFF_K     = 6400000;
constexpr size_t OFF_V     = 12800000;
constexpr size_t OFF_S     = 19200000;
constexpr size_t OFF_DENOM = 25600000;  // N*4 floats
constexpr size_t OFF_GSUM  = 25800000;  // 64
constexpr size_t OFF_GVAR  = 25800064;  // 64
constexpr size_t OFF_GCNT  = 25800128;  // 64 ints
constexpr size_t OFF_OUT   = OFF_Q;
constexpr size_t OFF_AGG   = OFF_K;

// ---------------- fused linear: q,k,v,s = x@W* + b* ----------------
// block = 256 threads, 16 nodes/block. thread = (node n = t&15, colgroup g = t>>4 -> 8 cols)
__global__ __launch_bounds__(256) void k_linear(
    const float* __restrict__ x,
    const float* __restrict__ Wq, const float* __restrict__ bq,
    const float* __restrict__ Wk, const float* __restrict__ bk,
    const float* __restrict__ Wv, const float* __restrict__ bv,
    const float* __restrict__ Wsm, const float* __restrict__ bs,
    float* __restrict__ q, float* __restrict__ k,
    float* __restrict__ v, float* __restrict__ s)
{
    __shared__ float xs[16][132];   // pad 132: float4-aligned, 2-way bank alias (free)
    const int t = threadIdx.x;
    const int n0 = blockIdx.x * 16;

    // cooperative load: 512 float4s
    for (int i = t; i < 512; i += 256) {
        int node = i >> 5, c = (i & 31) * 4;
        float4 val = *(const float4*)&x[(size_t)(n0 + node) * 128 + c];
        *(float4*)&xs[node][c] = val;
    }
    __syncthreads();

    const int n = t & 15, g = t >> 4;
    const int gn = n0 + n;
    const float* Wm[4] = {Wq, Wk, Wv, Wsm};
    const float* Bm[4] = {bq, bk, bv, bs};
    float* Om[4] = {q, k, v, s};

    #pragma unroll
    for (int mat = 0; mat < 4; ++mat) {
        const float* __restrict__ W = Wm[mat];
        float acc[8];
        #pragma unroll
        for (int j = 0; j < 8; ++j) acc[j] = Bm[mat][g * 8 + j];
        #pragma unroll 4
        for (int kk = 0; kk < 128; ++kk) {
            float xv = xs[n][kk];
            float4 w0 = *(const float4*)&W[kk * 128 + g * 8];
            float4 w1 = *(const float4*)&W[kk * 128 + g * 8 + 4];
            acc[0] += xv * w0.x; acc[1] += xv * w0.y;
            acc[2] += xv * w0.z; acc[3] += xv * w0.w;
            acc[4] += xv * w1.x; acc[5] += xv * w1.y;
            acc[6] += xv * w1.z; acc[7] += xv * w1.w;
        }
        float* __restrict__ O = Om[mat];
        *(float4*)&O[(size_t)gn * 128 + g * 8]     = make_float4(acc[0], acc[1], acc[2], acc[3]);
        *(float4*)&O[(size_t)gn * 128 + g * 8 + 4] = make_float4(acc[4], acc[5], acc[6], acc[7]);
    }
}

// ---------------- per-edge logits + exp + denom ----------------
// thread = (e, h). exp WITHOUT max-subtraction (alpha ~ N(0,1), softmax identical).
__global__ __launch_bounds__(256) void k_alpha(
    const float* __restrict__ q, const float* __restrict__ k,
    const int* __restrict__ src, const int* __restrict__ dst,
    float* __restrict__ exbuf /* d_out attn region */, float* __restrict__ denom)
{
    int idx = blockIdx.x * 256 + threadIdx.x;  // E*4 exact
    int e = idx >> 2, h = idx & 3;
    int d = dst[e], sn = src[e];
    const float4* qp = (const float4*)&q[(size_t)d  * 128 + h * 32];
    const float4* kp = (const float4*)&k[(size_t)sn * 128 + h * 32];
    float acc = 0.f;
    #pragma unroll
    for (int i = 0; i < 8; ++i) {
        float4 a = qp[i], b = kp[i];
        acc += a.x * b.x + a.y * b.y + a.z * b.z + a.w * b.w;
    }
    float ex = __expf(acc * RSQRT_D);
    exbuf[idx] = ex;
    atomicAdd(&denom[d * 4 + h], ex);
}

// ---------------- normalize attn in place ----------------
__global__ __launch_bounds__(256) void k_norm(
    float* __restrict__ attn, const float* __restrict__ denom,
    const int* __restrict__ dst)
{
    int idx = blockIdx.x * 256 + threadIdx.x;  // E*4 exact
    int e = idx >> 2, h = idx & 3;
    attn[idx] = attn[idx] / (denom[dst[e] * 4 + h] + 1e-16f);
}

// ---------------- aggregate attn * v[src] into agg[dst] ----------------
// thread = (e, 4-channel group)
__global__ __launch_bounds__(256) void k_agg(
    const float* __restrict__ v,
    const int* __restrict__ src, const int* __restrict__ dst,
    const float* __restrict__ attn, float* __restrict__ agg)
{
    int tid = blockIdx.x * 256 + threadIdx.x;  // E*32 exact
    int e = tid >> 5;
    int c = (tid & 31) * 4;
    int h = c >> 5;
    int d = dst[e], sn = src[e];
    float a = attn[e * 4 + h];
    float4 vv = *(const float4*)&v[(size_t)sn * 128 + c];
    float* ap = &agg[(size_t)d * 128 + c];
    atomicAdd(ap + 0, a * vv.x);
    atomicAdd(ap + 1, a * vv.y);
    atomicAdd(ap + 2, a * vv.z);
    atomicAdd(ap + 3, a * vv.w);
}

// ---------------- out = agg + skip; per-graph sum & count ----------------
// block = 256 threads = 32 nodes; thread = (node_local = t>>3, part = t&7 -> 16 ch)
__global__ __launch_bounds__(256) void k_outstats(
    const float* __restrict__ agg, const float* __restrict__ s,
    const int* __restrict__ batch, float* __restrict__ out,
    float* __restrict__ gsum, int* __restrict__ gcnt)
{
    __shared__ float nsum[32];
    __shared__ int   ngr[32];
    const int t = threadIdx.x;
    const int nl = t >> 3, part = t & 7;
    const int n = blockIdx.x * 32 + nl;
    float lsum = 0.f;
    if (n < N_NODES) {
        size_t base = (size_t)n * 128 + part * 16;
        #pragma unroll
        for (int i = 0; i < 4; ++i) {
            float4 a = *(const float4*)&agg[base + i * 4];
            float4 b = *(const float4*)&s[base + i * 4];
            float4 o = make_float4(a.x + b.x, a.y + b.y, a.z + b.z, a.w + b.w);
            *(float4*)&out[base + i * 4] = o;
            lsum += o.x + o.y + o.z + o.w;
        }
    }
    lsum += __shfl_xor(lsum, 1);
    lsum += __shfl_xor(lsum, 2);
    lsum += __shfl_xor(lsum, 4);
    if (part == 0) { nsum[nl] = lsum; ngr[nl] = (n < N_NODES) ? batch[n] : -1; }
    __syncthreads();
    if (t == 0) {  // batch sorted -> ~1-2 runs per block
        float acc = 0.f; int cg = ngr[0], cnt = 0;
        for (int i = 0; i < 32; ++i) {
            int g = ngr[i];
            if (g != cg) {
                if (cg >= 0) { atomicAdd(&gsum[cg], acc); atomicAdd(&gcnt[cg], cnt); }
                acc = 0.f; cnt = 0; cg = g;
            }
            acc += nsum[i]; ++cnt;
        }
        if (cg >= 0) { atomicAdd(&gsum[cg], acc); atomicAdd(&gcnt[cg], cnt); }
    }
}

// ---------------- per-graph centered sum of squares ----------------
__global__ __launch_bounds__(256) void k_var(
    const float* __restrict__ out, const int* __restrict__ batch,
    const float* __restrict__ gsum, const int* __restrict__ gcnt,
    float* __restrict__ gvar)
{
    __shared__ float nsum[32];
    __shared__ int   ngr[32];
    const int t = threadIdx.x;
    const int nl = t >> 3, part = t & 7;
    const int n = blockIdx.x * 32 + nl;
    float lsum = 0.f;
    if (n < N_NODES) {
        int g = batch[n];
        float mean = gsum[g] / (fmaxf((float)gcnt[g], 1.f) * 128.f);
        size_t base = (size_t)n * 128 + part * 16;
        #pragma unroll
        for (int i = 0; i < 4; ++i) {
            float4 o = *(const float4*)&out[base + i * 4];
            float dx = o.x - mean, dy = o.y - mean, dz = o.z - mean, dw = o.w - mean;
            lsum += dx * dx + dy * dy + dz * dz + dw * dw;
        }
    }
    lsum += __shfl_xor(lsum, 1);
    lsum += __shfl_xor(lsum, 2);
    lsum += __shfl_xor(lsum, 4);
    if (part == 0) { nsum[nl] = lsum; ngr[nl] = (n < N_NODES) ? batch[n] : -1; }
    __syncthreads();
    if (t == 0) {
        float acc = 0.f; int cg = ngr[0];
        for (int i = 0; i < 32; ++i) {
            int g = ngr[i];
            if (g != cg) {
                if (cg >= 0) atomicAdd(&gvar[cg], acc);
                acc = 0.f; cg = g;
            }
            acc += nsum[i];
        }
        if (cg >= 0) atomicAdd(&gvar[cg], acc);
    }
}

// ---------------- LayerNorm affine + LeakyReLU ----------------
__global__ __launch_bounds__(256) void k_final(
    const float* __restrict__ out, const int* __restrict__ batch,
    const float* __restrict__ gsum, const float* __restrict__ gvar,
    const int* __restrict__ gcnt,
    const float* __restrict__ lnw, const float* __restrict__ lnb,
    float* __restrict__ y)
{
    int idx = blockIdx.x * 256 + threadIdx.x;  // N*128 exact
    int n = idx >> 7, c = idx & 127;
    int g = batch[n];
    float norm = fmaxf((float)gcnt[g], 1.f) * 128.f;
    float mean = gsum[g] / norm;
    float var  = gvar[g] / norm;
    float inv  = rsqrtf(var + 1e-5f);
    float val  = (out[idx] - mean) * inv * lnw[c] + lnb[c];
    y[idx] = val > 0.f ? val : 0.01f * val;
}

extern "C" void kernel_launch(void* const* d_in, const int* in_sizes, int n_in,
                              void* d_out, int out_size, void* d_ws, size_t ws_size,
                              hipStream_t stream)
{
    (void)in_sizes; (void)n_in; (void)out_size; (void)ws_size;
    const float* x    = (const float*)d_in[0];
    const int*   ei   = (const int*)  d_in[1];
    const int*   batch= (const int*)  d_in[2];
    const float* Wq   = (const float*)d_in[3];
    const float* bq   = (const float*)d_in[4];
    const float* Wk   = (const float*)d_in[5];
    const float* bk   = (const float*)d_in[6];
    const float* Wv   = (const float*)d_in[7];
    const float* bv   = (const float*)d_in[8];
    const float* Wsm  = (const float*)d_in[9];
    const float* bs   = (const float*)d_in[10];
    const float* lnw  = (const float*)d_in[11];
    const float* lnb  = (const float*)d_in[12];

    float* outp = (float*)d_out;
    float* ws   = (float*)d_ws;

    const int* srcI = ei;             // edge_index[0]
    const int* dstI = ei + N_EDGES;   // edge_index[1]

    float* q     = ws + OFF_Q;
    float* k     = ws + OFF_K;
    float* v     = ws + OFF_V;
    float* s     = ws + OFF_S;
    float* denom = ws + OFF_DENOM;
    float* gsum  = ws + OFF_GSUM;
    float* gvar  = ws + OFF_GVAR;
    int*   gcnt  = (int*)(ws + OFF_GCNT);
    float* outb  = ws + OFF_OUT;   // alias q
    float* agg   = ws + OFF_AGG;   // alias k
    float* attn  = outp + Y_SIZE;

    // zero denom + graph stats (contiguous region)
    hipMemsetAsync(denom, 0, (size_t)(N_NODES * 4 + 192) * sizeof(float), stream);

    k_linear<<<N_NODES / 16, 256, 0, stream>>>(x, Wq, bq, Wk, bk, Wv, bv, Wsm, bs,
                                               q, k, v, s);
    k_alpha<<<(N_EDGES * 4) / 256, 256, 0, stream>>>(q, k, srcI, dstI, attn, denom);
    k_norm<<<(N_EDGES * 4) / 256, 256, 0, stream>>>(attn, denom, dstI);
    // k is dead now; zero agg (aliases k)
    hipMemsetAsync(agg, 0, (size_t)Y_SIZE * sizeof(float), stream);
    k_agg<<<(N_EDGES * 32) / 256, 256, 0, stream>>>(v, srcI, dstI, attn, agg);
    k_outstats<<<(N_NODES + 31) / 32, 256, 0, stream>>>(agg, s, batch, outb, gsum, gcnt);
    k_var<<<(N_NODES + 31) / 32, 256, 0, stream>>>(outb, batch, gsum, gcnt, gvar);
    k_final<<<Y_SIZE / 256, 256, 0, stream>>>(outb, batch, gsum, gvar, gcnt,
                                              lnw, lnb, outp);
}

// Round 2
// 842.014 us; speedup vs baseline: 2.3298x; 2.3298x over previous
//
#include <hip/hip_runtime.h>

constexpr int N_NODES = 50000;
constexpr int N_EDGES = 800000;
constexpr int HIDDEN  = 128;
constexpr float RSQRT_D = 0.17677669529663687f;  // 1/sqrt(32)
constexpr int Y_SIZE = N_NODES * HIDDEN;         // 6,400,000

// ---- ws layout (float offsets). q,k,v,s live through k_fused; out lives in
// d_out's y region (k_final does an in-place elementwise rewrite - safe). ----
constexpr size_t OFF_Q      = 0;
constexpr size_t OFF_K      = 6400000;
constexpr size_t OFF_V      = 12800000;
constexpr size_t OFF_S      = 19200000;
constexpr size_t OFF_DENOM  = 25600000;  // N*4 floats (written non-atomically by k_fused)
constexpr size_t OFF_GSUM   = 25800000;  // 64
constexpr size_t OFF_GVAR   = 25800064;  // 64
constexpr size_t OFF_GCNT   = 25800128;  // 64 ints
constexpr size_t OFF_DEG    = 25800192;  // 50000 ints
constexpr size_t OFF_OFFS   = 25850192;  // 50001 ints
constexpr size_t OFF_CURSOR = 25900224;  // 50000 ints
constexpr size_t OFF_CSRSRC = 25950224;  // 800000 ints
constexpr size_t OFF_CSREID = 26750224;  // 800000 ints
// end = 27,550,224 floats ~= 110 MB

// ---------------- fused linear: q,k,v,s = x@W* + b* ----------------
__global__ __launch_bounds__(256) void k_linear(
    const float* __restrict__ x,
    const float* __restrict__ Wq, const float* __restrict__ bq,
    const float* __restrict__ Wk, const float* __restrict__ bk,
    const float* __restrict__ Wv, const float* __restrict__ bv,
    const float* __restrict__ Wsm, const float* __restrict__ bs,
    float* __restrict__ q, float* __restrict__ k,
    float* __restrict__ v, float* __restrict__ s)
{
    __shared__ float xs[16][132];
    const int t = threadIdx.x;
    const int n0 = blockIdx.x * 16;

    for (int i = t; i < 512; i += 256) {
        int node = i >> 5, c = (i & 31) * 4;
        float4 val = *(const float4*)&x[(size_t)(n0 + node) * 128 + c];
        *(float4*)&xs[node][c] = val;
    }
    __syncthreads();

    const int n = t & 15, g = t >> 4;
    const int gn = n0 + n;
    const float* Wm[4] = {Wq, Wk, Wv, Wsm};
    const float* Bm[4] = {bq, bk, bv, bs};
    float* Om[4] = {q, k, v, s};

    #pragma unroll
    for (int mat = 0; mat < 4; ++mat) {
        const float* __restrict__ W = Wm[mat];
        float acc[8];
        #pragma unroll
        for (int j = 0; j < 8; ++j) acc[j] = Bm[mat][g * 8 + j];
        #pragma unroll 4
        for (int kk = 0; kk < 128; ++kk) {
            float xv = xs[n][kk];
            float4 w0 = *(const float4*)&W[kk * 128 + g * 8];
            float4 w1 = *(const float4*)&W[kk * 128 + g * 8 + 4];
            acc[0] += xv * w0.x; acc[1] += xv * w0.y;
            acc[2] += xv * w0.z; acc[3] += xv * w0.w;
            acc[4] += xv * w1.x; acc[5] += xv * w1.y;
            acc[6] += xv * w1.z; acc[7] += xv * w1.w;
        }
        float* __restrict__ O = Om[mat];
        *(float4*)&O[(size_t)gn * 128 + g * 8]     = make_float4(acc[0], acc[1], acc[2], acc[3]);
        *(float4*)&O[(size_t)gn * 128 + g * 8 + 4] = make_float4(acc[4], acc[5], acc[6], acc[7]);
    }
}

// ---------------- CSR build: histogram / scan / scatter ----------------
__global__ __launch_bounds__(256) void k_hist(const int* __restrict__ dst,
                                              int* __restrict__ deg)
{
    int e = blockIdx.x * 256 + threadIdx.x;  // E exact
    atomicAdd(&deg[dst[e]], 1);
}

__global__ __launch_bounds__(1024) void k_scan(const int* __restrict__ deg,
                                               int* __restrict__ offs,
                                               int* __restrict__ cursor)
{
    __shared__ int part[1024];
    const int t = threadIdx.x;
    const int start = t * 49;          // 1024*49 = 50176 >= 50000
    int sum = 0;
    for (int i = 0; i < 49; ++i) {
        int idx = start + i;
        if (idx < N_NODES) sum += deg[idx];
    }
    part[t] = sum;
    __syncthreads();
    for (int off = 1; off < 1024; off <<= 1) {
        int tmp = (t >= off) ? part[t - off] : 0;
        __syncthreads();
        part[t] += tmp;
        __syncthreads();
    }
    int base = (t == 0) ? 0 : part[t - 1];
    for (int i = 0; i < 49; ++i) {
        int idx = start + i;
        if (idx < N_NODES) {
            offs[idx] = base;
            cursor[idx] = base;
            base += deg[idx];
        }
    }
    if (t == 1023) offs[N_NODES] = part[1023];
}

__global__ __launch_bounds__(256) void k_scatter(
    const int* __restrict__ src, const int* __restrict__ dst,
    int* __restrict__ cursor, int* __restrict__ csr_src, int* __restrict__ csr_eid)
{
    int e = blockIdx.x * 256 + threadIdx.x;  // E exact
    int d = dst[e];
    int pos = atomicAdd(&cursor[d], 1);
    csr_src[pos] = src[e];
    csr_eid[pos] = e;
}

// ---------------- fused: logits + exp + denom + aggregate + skip ----------------
// One 64-lane wave per dst node; lane l owns channels (2l, 2l+1); head = l>>4.
__global__ __launch_bounds__(256) void k_fused(
    const float* __restrict__ q, const float* __restrict__ k,
    const float* __restrict__ v, const float* __restrict__ s,
    const int* __restrict__ offs, const int* __restrict__ csr_src,
    const int* __restrict__ csr_eid,
    float* __restrict__ exbuf,   // d_out attn region: raw exp values
    float* __restrict__ denom,   // [N,4] head denominators (non-atomic)
    float* __restrict__ outb)    // d_out y region: agg + skip
{
    const int t = threadIdx.x;
    const int lane = t & 63;
    const int n = blockIdx.x * 4 + (t >> 6);  // grid*4 == N exact
    const int begin = offs[n], end = offs[n + 1];
    const float2 qv = *(const float2*)&q[(size_t)n * 128 + lane * 2];
    float acc0 = 0.f, acc1 = 0.f, dsum = 0.f;
    for (int i = begin; i < end; ++i) {
        const int sn  = csr_src[i];
        const int eid = csr_eid[i];
        const float2 kv = *(const float2*)&k[(size_t)sn * 128 + lane * 2];
        const float2 vv = *(const float2*)&v[(size_t)sn * 128 + lane * 2];
        float p = qv.x * kv.x + qv.y * kv.y;
        p += __shfl_xor(p, 1);
        p += __shfl_xor(p, 2);
        p += __shfl_xor(p, 4);
        p += __shfl_xor(p, 8);
        const float ex = __expf(p * RSQRT_D);
        dsum += ex;
        acc0 += ex * vv.x;
        acc1 += ex * vv.y;
        if ((lane & 15) == 0) exbuf[eid * 4 + (lane >> 4)] = ex;
    }
    if ((lane & 15) == 0) denom[n * 4 + (lane >> 4)] = dsum;
    const float rdn = 1.f / (dsum + 1e-16f);
    const float2 sv = *(const float2*)&s[(size_t)n * 128 + lane * 2];
    float2 o = make_float2(acc0 * rdn + sv.x, acc1 * rdn + sv.y);
    *(float2*)&outb[(size_t)n * 128 + lane * 2] = o;
}

// ---------------- normalize attn in place ----------------
__global__ __launch_bounds__(256) void k_norm(
    float* __restrict__ attn, const float* __restrict__ denom,
    const int* __restrict__ dst)
{
    int idx = blockIdx.x * 256 + threadIdx.x;  // E*4 exact
    int e = idx >> 2, h = idx & 3;
    attn[idx] = attn[idx] / (denom[dst[e] * 4 + h] + 1e-16f);
}

// ---------------- per-graph sum & count over out ----------------
__global__ __launch_bounds__(256) void k_sum(
    const float* __restrict__ out, const int* __restrict__ batch,
    float* __restrict__ gsum, int* __restrict__ gcnt)
{
    __shared__ float nsum[32];
    __shared__ int   ngr[32];
    const int t = threadIdx.x;
    const int nl = t >> 3, part = t & 7;
    const int n = blockIdx.x * 32 + nl;
    float lsum = 0.f;
    if (n < N_NODES) {
        size_t base = (size_t)n * 128 + part * 16;
        #pragma unroll
        for (int i = 0; i < 4; ++i) {
            float4 o = *(const float4*)&out[base + i * 4];
            lsum += o.x + o.y + o.z + o.w;
        }
    }
    lsum += __shfl_xor(lsum, 1);
    lsum += __shfl_xor(lsum, 2);
    lsum += __shfl_xor(lsum, 4);
    if (part == 0) { nsum[nl] = lsum; ngr[nl] = (n < N_NODES) ? batch[n] : -1; }
    __syncthreads();
    if (t == 0) {
        float acc = 0.f; int cg = ngr[0], cnt = 0;
        for (int i = 0; i < 32; ++i) {
            int g = ngr[i];
            if (g != cg) {
                if (cg >= 0) { atomicAdd(&gsum[cg], acc); atomicAdd(&gcnt[cg], cnt); }
                acc = 0.f; cnt = 0; cg = g;
            }
            acc += nsum[i]; ++cnt;
        }
        if (cg >= 0) { atomicAdd(&gsum[cg], acc); atomicAdd(&gcnt[cg], cnt); }
    }
}

// ---------------- per-graph centered sum of squares ----------------
__global__ __launch_bounds__(256) void k_var(
    const float* __restrict__ out, const int* __restrict__ batch,
    const float* __restrict__ gsum, const int* __restrict__ gcnt,
    float* __restrict__ gvar)
{
    __shared__ float nsum[32];
    __shared__ int   ngr[32];
    const int t = threadIdx.x;
    const int nl = t >> 3, part = t & 7;
    const int n = blockIdx.x * 32 + nl;
    float lsum = 0.f;
    if (n < N_NODES) {
        int g = batch[n];
        float mean = gsum[g] / (fmaxf((float)gcnt[g], 1.f) * 128.f);
        size_t base = (size_t)n * 128 + part * 16;
        #pragma unroll
        for (int i = 0; i < 4; ++i) {
            float4 o = *(const float4*)&out[base + i * 4];
            float dx = o.x - mean, dy = o.y - mean, dz = o.z - mean, dw = o.w - mean;
            lsum += dx * dx + dy * dy + dz * dz + dw * dw;
        }
    }
    lsum += __shfl_xor(lsum, 1);
    lsum += __shfl_xor(lsum, 2);
    lsum += __shfl_xor(lsum, 4);
    if (part == 0) { nsum[nl] = lsum; ngr[nl] = (n < N_NODES) ? batch[n] : -1; }
    __syncthreads();
    if (t == 0) {
        float acc = 0.f; int cg = ngr[0];
        for (int i = 0; i < 32; ++i) {
            int g = ngr[i];
            if (g != cg) {
                if (cg >= 0) atomicAdd(&gvar[cg], acc);
                acc = 0.f; cg = g;
            }
            acc += nsum[i];
        }
        if (cg >= 0) atomicAdd(&gvar[cg], acc);
    }
}

// ---------------- LayerNorm affine + LeakyReLU (in-place on y region) ----------------
__global__ __launch_bounds__(256) void k_final(
    const float* __restrict__ out, const int* __restrict__ batch,
    const float* __restrict__ gsum, const float* __restrict__ gvar,
    const int* __restrict__ gcnt,
    const float* __restrict__ lnw, const float* __restrict__ lnb,
    float* __restrict__ y)
{
    int idx = blockIdx.x * 256 + threadIdx.x;  // N*128 exact
    int n = idx >> 7, c = idx & 127;
    int g = batch[n];
    float norm = fmaxf((float)gcnt[g], 1.f) * 128.f;
    float mean = gsum[g] / norm;
    float var  = gvar[g] / norm;
    float inv  = rsqrtf(var + 1e-5f);
    float val  = (out[idx] - mean) * inv * lnw[c] + lnb[c];
    y[idx] = val > 0.f ? val : 0.01f * val;
}

extern "C" void kernel_launch(void* const* d_in, const int* in_sizes, int n_in,
                              void* d_out, int out_size, void* d_ws, size_t ws_size,
                              hipStream_t stream)
{
    (void)in_sizes; (void)n_in; (void)out_size; (void)ws_size;
    const float* x    = (const float*)d_in[0];
    const int*   ei   = (const int*)  d_in[1];
    const int*   batch= (const int*)  d_in[2];
    const float* Wq   = (const float*)d_in[3];
    const float* bq   = (const float*)d_in[4];
    const float* Wk   = (const float*)d_in[5];
    const float* bk   = (const float*)d_in[6];
    const float* Wv   = (const float*)d_in[7];
    const float* bv   = (const float*)d_in[8];
    const float* Wsm  = (const float*)d_in[9];
    const float* bs   = (const float*)d_in[10];
    const float* lnw  = (const float*)d_in[11];
    const float* lnb  = (const float*)d_in[12];

    float* outp = (float*)d_out;
    float* ws   = (float*)d_ws;

    const int* srcI = ei;             // edge_index[0]
    const int* dstI = ei + N_EDGES;   // edge_index[1]

    float* q       = ws + OFF_Q;
    float* k       = ws + OFF_K;
    float* v       = ws + OFF_V;
    float* s       = ws + OFF_S;
    float* denom   = ws + OFF_DENOM;
    float* gsum    = ws + OFF_GSUM;
    float* gvar    = ws + OFF_GVAR;
    int*   gcnt    = (int*)(ws + OFF_GCNT);
    int*   deg     = (int*)(ws + OFF_DEG);
    int*   offs    = (int*)(ws + OFF_OFFS);
    int*   cursor  = (int*)(ws + OFF_CURSOR);
    int*   csr_src = (int*)(ws + OFF_CSRSRC);
    int*   csr_eid = (int*)(ws + OFF_CSREID);

    float* outb = outp;               // y region doubles as pre-LN buffer
    float* attn = outp + Y_SIZE;      // raw ex, then normalized in place

    // zero gsum/gvar/gcnt + deg (contiguous)
    hipMemsetAsync(gsum, 0, (size_t)(192 + N_NODES) * sizeof(float), stream);

    k_linear<<<N_NODES / 16, 256, 0, stream>>>(x, Wq, bq, Wk, bk, Wv, bv, Wsm, bs,
                                               q, k, v, s);
    k_hist<<<N_EDGES / 256, 256, 0, stream>>>(dstI, deg);
    k_scan<<<1, 1024, 0, stream>>>(deg, offs, cursor);
    k_scatter<<<N_EDGES / 256, 256, 0, stream>>>(srcI, dstI, cursor, csr_src, csr_eid);
    k_fused<<<N_NODES / 4, 256, 0, stream>>>(q, k, v, s, offs, csr_src, csr_eid,
                                             attn, denom, outb);
    k_norm<<<(N_EDGES * 4) / 256, 256, 0, stream>>>(attn, denom, dstI);
    k_sum<<<(N_NODES + 31) / 32, 256, 0, stream>>>(outb, batch, gsum, gcnt);
    k_var<<<(N_NODES + 31) / 32, 256, 0, stream>>>(outb, batch, gsum, gcnt, gvar);
    k_final<<<Y_SIZE / 256, 256, 0, stream>>>(outb, batch, gsum, gvar, gcnt,
                                              lnw, lnb, outp);
}

// Round 3
// 492.030 us; speedup vs baseline: 3.9869x; 1.7113x over previous
//
#include <hip/hip_runtime.h>

constexpr int N_NODES = 50000;
constexpr int N_EDGES = 800000;
constexpr int HIDDEN  = 128;
constexpr float RSQRT_D = 0.17677669529663687f;  // 1/sqrt(32)
constexpr int Y_SIZE = N_NODES * HIDDEN;         // 6,400,000
constexpr int M_PAD  = 50048;                    // 391 * 128

// ---- ws layout (float offsets) ----
constexpr size_t OFF_Q      = 0;
constexpr size_t OFF_K      = 6400000;
constexpr size_t OFF_V      = 12800000;
constexpr size_t OFF_S      = 19200000;
constexpr size_t OFF_DENOM  = 25600000;  // N*4 floats; ALSO hosts Wt_swz (dead before k_fused)
constexpr size_t OFF_GSUM   = 25800000;  // 64
constexpr size_t OFF_GVAR   = 25800064;  // 64
constexpr size_t OFF_GCNT   = 25800128;  // 64 ints
constexpr size_t OFF_DEG    = 25800192;  // 50000 ints
constexpr size_t OFF_OFFS   = 25850192;  // 50001 ints
constexpr size_t OFF_CURSOR = 25900224;  // 50000 ints
constexpr size_t OFF_CSRSRC = 25950224;  // 800000 ints
constexpr size_t OFF_CSREID = 26750224;  // 800000 ints

typedef __attribute__((ext_vector_type(8))) short bf16x8;
typedef __attribute__((ext_vector_type(4))) float f32x4;

__device__ __forceinline__ short f2bf(float f) {  // RNE f32 -> bf16 bits
    unsigned u = __float_as_uint(f);
    unsigned r = (u + 0x7fff + ((u >> 16) & 1)) >> 16;
    return (short)r;
}

__device__ __forceinline__ void gload_lds16(const void* g, void* l) {
    __builtin_amdgcn_global_load_lds(
        (const __attribute__((address_space(1))) void*)g,
        (__attribute__((address_space(3))) void*)l, 16, 0, 0);
}

// ---------------- x f32 -> bf16, padded to M_PAD rows, XOR-swizzled ----------------
// Row = 256 B = 16 chunks of 16 B; chunk ci stored at ci ^ (row & 7).
__global__ __launch_bounds__(256) void k_cvt_x(const float* __restrict__ x,
                                               short* __restrict__ xs)
{
    int tid = blockIdx.x * 256 + threadIdx.x;  // M_PAD*16 exact
    int row = tid >> 4, ci = tid & 15;
    short o[8];
    if (row < N_NODES) {
        float4 a = *(const float4*)&x[(size_t)row * 128 + ci * 8];
        float4 b = *(const float4*)&x[(size_t)row * 128 + ci * 8 + 4];
        o[0] = f2bf(a.x); o[1] = f2bf(a.y); o[2] = f2bf(a.z); o[3] = f2bf(a.w);
        o[4] = f2bf(b.x); o[5] = f2bf(b.y); o[6] = f2bf(b.z); o[7] = f2bf(b.w);
    } else {
        #pragma unroll
        for (int j = 0; j < 8; ++j) o[j] = 0;
    }
    int cs = ci ^ (row & 7);
    *(int4*)&xs[(size_t)row * 128 + cs * 8] = *(int4*)o;
}

// ---------------- W [K=128][N=128] f32 -> Wt bf16 [n][k], swizzled ----------------
__global__ __launch_bounds__(256) void k_cvt_w(
    const float* __restrict__ Wq, const float* __restrict__ Wk,
    const float* __restrict__ Wv, const float* __restrict__ Wsm,
    short* __restrict__ wt)
{
    int tid = blockIdx.x * 256 + threadIdx.x;  // 4*128*16 = 8192 exact
    int mat = tid >> 11, n = (tid >> 4) & 127, kg = tid & 15;
    const float* W = (mat == 0) ? Wq : (mat == 1) ? Wk : (mat == 2) ? Wv : Wsm;
    short o[8];
    #pragma unroll
    for (int j = 0; j < 8; ++j) o[j] = f2bf(W[(kg * 8 + j) * 128 + n]);
    int cs = kg ^ (n & 7);
    *(int4*)&wt[mat * 16384 + n * 128 + cs * 8] = *(int4*)o;
}

// ---------------- MFMA GEMM: [M_PAD x 128] x [128 x 128] per mat ----------------
// Block: 256 thr = 4 waves (2x2), 128x128 tile; wave = 64x64; K staged whole.
__global__ __launch_bounds__(256) void k_mm(
    const short* __restrict__ xs, const short* __restrict__ wt,
    const float* __restrict__ bq, const float* __restrict__ bk,
    const float* __restrict__ bv, const float* __restrict__ bs,
    float* __restrict__ q, float* __restrict__ k,
    float* __restrict__ v, float* __restrict__ s)
{
    __shared__ __align__(16) char As[32768];
    __shared__ __align__(16) char Bs[32768];
    const int t = threadIdx.x, lane = t & 63, wv = t >> 6;
    const int bm = blockIdx.x >> 2, nt = blockIdx.x & 3;
    const int m0 = bm * 128;

    const char* gA = (const char*)xs + (size_t)m0 * 256;
    const char* gB = (const char*)wt + nt * 32768;
    #pragma unroll
    for (int i = 0; i < 8; ++i) {
        int chunk = wv * 8 + i;
        gload_lds16(gA + chunk * 1024 + lane * 16, As + chunk * 1024);
        gload_lds16(gB + chunk * 1024 + lane * 16, Bs + chunk * 1024);
    }

    const float* Bb = (nt == 0) ? bq : (nt == 1) ? bk : (nt == 2) ? bv : bs;
    const int wm = wv >> 1, wn = wv & 1;
    f32x4 acc[4][4];
    #pragma unroll
    for (int nf = 0; nf < 4; ++nf) {
        float bc = Bb[wn * 64 + nf * 16 + (lane & 15)];
        #pragma unroll
        for (int mf = 0; mf < 4; ++mf) acc[mf][nf] = (f32x4){bc, bc, bc, bc};
    }
    __syncthreads();

    #pragma unroll
    for (int ks = 0; ks < 4; ++ks) {
        bf16x8 af[4], bfr[4];
        const int cbase = ks * 64 + ((lane >> 4) << 4);
        #pragma unroll
        for (int mf = 0; mf < 4; ++mf) {
            int mr = wm * 64 + mf * 16 + (lane & 15);
            af[mf] = *(const bf16x8*)(As + mr * 256 + (cbase ^ ((mr & 7) << 4)));
        }
        #pragma unroll
        for (int nf = 0; nf < 4; ++nf) {
            int nc = wn * 64 + nf * 16 + (lane & 15);
            bfr[nf] = *(const bf16x8*)(Bs + nc * 256 + (cbase ^ ((nc & 7) << 4)));
        }
        #pragma unroll
        for (int mf = 0; mf < 4; ++mf)
            #pragma unroll
            for (int nf = 0; nf < 4; ++nf)
                acc[mf][nf] = __builtin_amdgcn_mfma_f32_16x16x32_bf16(
                    af[mf], bfr[nf], acc[mf][nf], 0, 0, 0);
    }

    float* O = (nt == 0) ? q : (nt == 1) ? k : (nt == 2) ? v : s;
    const int colbase = wn * 64 + (lane & 15);
    #pragma unroll
    for (int mf = 0; mf < 4; ++mf) {
        int rowb = m0 + wm * 64 + mf * 16 + ((lane >> 4) << 2);
        #pragma unroll
        for (int nf = 0; nf < 4; ++nf) {
            int col = colbase + nf * 16;
            #pragma unroll
            for (int r = 0; r < 4; ++r) {
                int node = rowb + r;
                if (node < N_NODES) O[(size_t)node * 128 + col] = acc[mf][nf][r];
            }
        }
    }
}

// ---------------- CSR build: histogram / scan / scatter ----------------
__global__ __launch_bounds__(256) void k_hist(const int* __restrict__ dst,
                                              int* __restrict__ deg)
{
    int e = blockIdx.x * 256 + threadIdx.x;  // E exact
    atomicAdd(&deg[dst[e]], 1);
}

__global__ __launch_bounds__(1024) void k_scan(const int* __restrict__ deg,
                                               int* __restrict__ offs,
                                               int* __restrict__ cursor)
{
    __shared__ int part[1024];
    const int t = threadIdx.x;
    const int start = t * 49;          // 1024*49 = 50176 >= 50000
    int sum = 0;
    for (int i = 0; i < 49; ++i) {
        int idx = start + i;
        if (idx < N_NODES) sum += deg[idx];
    }
    part[t] = sum;
    __syncthreads();
    for (int off = 1; off < 1024; off <<= 1) {
        int tmp = (t >= off) ? part[t - off] : 0;
        __syncthreads();
        part[t] += tmp;
        __syncthreads();
    }
    int base = (t == 0) ? 0 : part[t - 1];
    for (int i = 0; i < 49; ++i) {
        int idx = start + i;
        if (idx < N_NODES) {
            offs[idx] = base;
            cursor[idx] = base;
            base += deg[idx];
        }
    }
    if (t == 1023) offs[N_NODES] = part[1023];
}

__global__ __launch_bounds__(256) void k_scatter(
    const int* __restrict__ src, const int* __restrict__ dst,
    int* __restrict__ cursor, int* __restrict__ csr_src, int* __restrict__ csr_eid)
{
    int e = blockIdx.x * 256 + threadIdx.x;  // E exact
    int d = dst[e];
    int pos = atomicAdd(&cursor[d], 1);
    csr_src[pos] = src[e];
    csr_eid[pos] = e;
}

// ---------------- fused: logits + exp + denom + aggregate + skip ----------------
__global__ __launch_bounds__(256) void k_fused(
    const float* __restrict__ q, const float* __restrict__ k,
    const float* __restrict__ v, const float* __restrict__ s,
    const int* __restrict__ offs, const int* __restrict__ csr_src,
    const int* __restrict__ csr_eid,
    float* __restrict__ exbuf, float* __restrict__ denom,
    float* __restrict__ outb)
{
    const int t = threadIdx.x;
    const int lane = t & 63;
    const int n = blockIdx.x * 4 + (t >> 6);  // grid*4 == N exact
    const int begin = offs[n], end = offs[n + 1];
    const float2 qv = *(const float2*)&q[(size_t)n * 128 + lane * 2];
    float acc0 = 0.f, acc1 = 0.f, dsum = 0.f;
    for (int i = begin; i < end; ++i) {
        const int sn  = csr_src[i];
        const int eid = csr_eid[i];
        const float2 kv = *(const float2*)&k[(size_t)sn * 128 + lane * 2];
        const float2 vv = *(const float2*)&v[(size_t)sn * 128 + lane * 2];
        float p = qv.x * kv.x + qv.y * kv.y;
        p += __shfl_xor(p, 1);
        p += __shfl_xor(p, 2);
        p += __shfl_xor(p, 4);
        p += __shfl_xor(p, 8);
        const float ex = __expf(p * RSQRT_D);
        dsum += ex;
        acc0 += ex * vv.x;
        acc1 += ex * vv.y;
        if ((lane & 15) == 0) exbuf[eid * 4 + (lane >> 4)] = ex;
    }
    if ((lane & 15) == 0) denom[n * 4 + (lane >> 4)] = dsum;
    const float rdn = 1.f / (dsum + 1e-16f);
    const float2 sv = *(const float2*)&s[(size_t)n * 128 + lane * 2];
    float2 o = make_float2(acc0 * rdn + sv.x, acc1 * rdn + sv.y);
    *(float2*)&outb[(size_t)n * 128 + lane * 2] = o;
}

// ---------------- normalize attn in place ----------------
__global__ __launch_bounds__(256) void k_norm(
    float* __restrict__ attn, const float* __restrict__ denom,
    const int* __restrict__ dst)
{
    int idx = blockIdx.x * 256 + threadIdx.x;  // E*4 exact
    int e = idx >> 2, h = idx & 3;
    attn[idx] = attn[idx] / (denom[dst[e] * 4 + h] + 1e-16f);
}

// ---------------- per-graph sum & count ----------------
__global__ __launch_bounds__(256) void k_sum(
    const float* __restrict__ out, const int* __restrict__ batch,
    float* __restrict__ gsum, int* __restrict__ gcnt)
{
    __shared__ float nsum[32];
    __shared__ int   ngr[32];
    const int t = threadIdx.x;
    const int nl = t >> 3, part = t & 7;
    const int n = blockIdx.x * 32 + nl;
    float lsum = 0.f;
    if (n < N_NODES) {
        size_t base = (size_t)n * 128 + part * 16;
        #pragma unroll
        for (int i = 0; i < 4; ++i) {
            float4 o = *(const float4*)&out[base + i * 4];
            lsum += o.x + o.y + o.z + o.w;
        }
    }
    lsum += __shfl_xor(lsum, 1);
    lsum += __shfl_xor(lsum, 2);
    lsum += __shfl_xor(lsum, 4);
    if (part == 0) { nsum[nl] = lsum; ngr[nl] = (n < N_NODES) ? batch[n] : -1; }
    __syncthreads();
    if (t == 0) {
        float acc = 0.f; int cg = ngr[0], cnt = 0;
        for (int i = 0; i < 32; ++i) {
            int g = ngr[i];
            if (g != cg) {
                if (cg >= 0) { atomicAdd(&gsum[cg], acc); atomicAdd(&gcnt[cg], cnt); }
                acc = 0.f; cnt = 0; cg = g;
            }
            acc += nsum[i]; ++cnt;
        }
        if (cg >= 0) { atomicAdd(&gsum[cg], acc); atomicAdd(&gcnt[cg], cnt); }
    }
}

// ---------------- per-graph centered sum of squares ----------------
__global__ __launch_bounds__(256) void k_var(
    const float* __restrict__ out, const int* __restrict__ batch,
    const float* __restrict__ gsum, const int* __restrict__ gcnt,
    float* __restrict__ gvar)
{
    __shared__ float nsum[32];
    __shared__ int   ngr[32];
    const int t = threadIdx.x;
    const int nl = t >> 3, part = t & 7;
    const int n = blockIdx.x * 32 + nl;
    float lsum = 0.f;
    if (n < N_NODES) {
        int g = batch[n];
        float mean = gsum[g] / (fmaxf((float)gcnt[g], 1.f) * 128.f);
        size_t base = (size_t)n * 128 + part * 16;
        #pragma unroll
        for (int i = 0; i < 4; ++i) {
            float4 o = *(const float4*)&out[base + i * 4];
            float dx = o.x - mean, dy = o.y - mean, dz = o.z - mean, dw = o.w - mean;
            lsum += dx * dx + dy * dy + dz * dz + dw * dw;
        }
    }
    lsum += __shfl_xor(lsum, 1);
    lsum += __shfl_xor(lsum, 2);
    lsum += __shfl_xor(lsum, 4);
    if (part == 0) { nsum[nl] = lsum; ngr[nl] = (n < N_NODES) ? batch[n] : -1; }
    __syncthreads();
    if (t == 0) {
        float acc = 0.f; int cg = ngr[0];
        for (int i = 0; i < 32; ++i) {
            int g = ngr[i];
            if (g != cg) {
                if (cg >= 0) atomicAdd(&gvar[cg], acc);
                acc = 0.f; cg = g;
            }
            acc += nsum[i];
        }
        if (cg >= 0) atomicAdd(&gvar[cg], acc);
    }
}

// ---------------- LayerNorm affine + LeakyReLU (in-place) ----------------
__global__ __launch_bounds__(256) void k_final(
    const float* __restrict__ out, const int* __restrict__ batch,
    const float* __restrict__ gsum, const float* __restrict__ gvar,
    const int* __restrict__ gcnt,
    const float* __restrict__ lnw, const float* __restrict__ lnb,
    float* __restrict__ y)
{
    int idx = blockIdx.x * 256 + threadIdx.x;  // N*128 exact
    int n = idx >> 7, c = idx & 127;
    int g = batch[n];
    float norm = fmaxf((float)gcnt[g], 1.f) * 128.f;
    float mean = gsum[g] / norm;
    float var  = gvar[g] / norm;
    float inv  = rsqrtf(var + 1e-5f);
    float val  = (out[idx] - mean) * inv * lnw[c] + lnb[c];
    y[idx] = val > 0.f ? val : 0.01f * val;
}

extern "C" void kernel_launch(void* const* d_in, const int* in_sizes, int n_in,
                              void* d_out, int out_size, void* d_ws, size_t ws_size,
                              hipStream_t stream)
{
    (void)in_sizes; (void)n_in; (void)out_size; (void)ws_size;
    const float* x    = (const float*)d_in[0];
    const int*   ei   = (const int*)  d_in[1];
    const int*   batch= (const int*)  d_in[2];
    const float* Wq   = (const float*)d_in[3];
    const float* bq   = (const float*)d_in[4];
    const float* Wk   = (const float*)d_in[5];
    const float* bk   = (const float*)d_in[6];
    const float* Wv   = (const float*)d_in[7];
    const float* bv   = (const float*)d_in[8];
    const float* Wsm  = (const float*)d_in[9];
    const float* bs   = (const float*)d_in[10];
    const float* lnw  = (const float*)d_in[11];
    const float* lnb  = (const float*)d_in[12];

    float* outp = (float*)d_out;
    float* ws   = (float*)d_ws;

    const int* srcI = ei;
    const int* dstI = ei + N_EDGES;

    float* q       = ws + OFF_Q;
    float* k       = ws + OFF_K;
    float* v       = ws + OFF_V;
    float* s       = ws + OFF_S;
    float* denom   = ws + OFF_DENOM;
    short* wt      = (short*)(ws + OFF_DENOM);  // dead before k_fused writes denom
    float* gsum    = ws + OFF_GSUM;
    float* gvar    = ws + OFF_GVAR;
    int*   gcnt    = (int*)(ws + OFF_GCNT);
    int*   deg     = (int*)(ws + OFF_DEG);
    int*   offs    = (int*)(ws + OFF_OFFS);
    int*   cursor  = (int*)(ws + OFF_CURSOR);
    int*   csr_src = (int*)(ws + OFF_CSRSRC);
    int*   csr_eid = (int*)(ws + OFF_CSREID);

    float* outb  = outp;                  // y region: x_swz first, then pre-LN out
    short* x_swz = (short*)outp;          // 12.8 MB, dead once k_mm finishes
    float* attn  = outp + Y_SIZE;

    // zero gsum/gvar/gcnt + deg
    hipMemsetAsync(gsum, 0, (size_t)(192 + N_NODES) * sizeof(float), stream);

    k_cvt_w<<<32, 256, 0, stream>>>(Wq, Wk, Wv, Wsm, wt);
    k_cvt_x<<<(M_PAD * 16) / 256, 256, 0, stream>>>(x, x_swz);
    k_mm<<<(M_PAD / 128) * 4, 256, 0, stream>>>(x_swz, wt, bq, bk, bv, bs, q, k, v, s);

    k_hist<<<N_EDGES / 256, 256, 0, stream>>>(dstI, deg);
    k_scan<<<1, 1024, 0, stream>>>(deg, offs, cursor);
    k_scatter<<<N_EDGES / 256, 256, 0, stream>>>(srcI, dstI, cursor, csr_src, csr_eid);
    k_fused<<<N_NODES / 4, 256, 0, stream>>>(q, k, v, s, offs, csr_src, csr_eid,
                                             attn, denom, outb);
    k_norm<<<(N_EDGES * 4) / 256, 256, 0, stream>>>(attn, denom, dstI);
    k_sum<<<(N_NODES + 31) / 32, 256, 0, stream>>>(outb, batch, gsum, gcnt);
    k_var<<<(N_NODES + 31) / 32, 256, 0, stream>>>(outb, batch, gsum, gcnt, gvar);
    k_final<<<Y_SIZE / 256, 256, 0, stream>>>(outb, batch, gsum, gvar, gcnt,
                                              lnw, lnb, outp);
}